// Round 1
// baseline (1958.924 us; speedup 1.0000x reference)
//
#include <hip/hip_runtime.h>
#include <hip/hip_bf16.h>

// Tree-LSTM over complete binary tree, depth 15.
// N=32767 nodes, state 2H=512, gates 4*2H=2048, vocab 32, emb 256.
// Key facts:
//  - x_proj depends only on types[i] (32 values) -> 32x2048 proj table.
//  - leaves (16383..32766) have zero child state -> no W_hh matvec.
//  - parent gather reads only first H=256 floats of each child's h/c.
//  - h is stored in d_out[node][512]; compact c state C256[node][256] in ws.

#define NNODES 32767
#define NT 16   // nodes per gemm tile

__device__ __forceinline__ float sigf(float x) { return 1.0f / (1.0f + __expf(-x)); }
__device__ __forceinline__ float tanhfast(float x) { return 2.0f / (1.0f + __expf(-2.0f * x)) - 1.0f; }

// proj[v][r] = dot(emb[v], W_ih[r]) + b_ih[r] + b_hh[r]
// grid 256 (32 vocab x 8 row-chunks), block 256
__global__ void proj_kernel(const float* __restrict__ emb, const float* __restrict__ W_ih,
                            const float* __restrict__ b_ih, const float* __restrict__ b_hh,
                            float* __restrict__ proj) {
    __shared__ float e[256];
    int v = blockIdx.x >> 3;
    int rc = blockIdx.x & 7;
    int t = threadIdx.x;
    e[t] = emb[v * 256 + t];
    __syncthreads();
    int r = rc * 256 + t;
    const float4* w4 = (const float4*)(W_ih + (size_t)r * 256);
    const float4* e4 = (const float4*)e;
    float acc = 0.f;
#pragma unroll 8
    for (int k = 0; k < 64; ++k) {
        float4 w = w4[k];
        float4 h = e4[k];
        acc += w.x * h.x + w.y * h.y + w.z * h.z + w.w * h.w;
    }
    proj[v * 2048 + r] = acc + b_ih[r] + b_hh[r];
}

// leaves: gates = proj[type]; c=h=0 coming in.
// grid 32768 (16384 leaves x 2 half-rows of j), block 256
__global__ void leaf_kernel(const int* __restrict__ types, const float* __restrict__ proj,
                            float* __restrict__ out, float* __restrict__ C256) {
    int bi = blockIdx.x;
    int node = 16383 + (bi >> 1);
    int j = ((bi & 1) << 8) + threadIdx.x;
    int tt = types[node];
    const float* p = proj + (size_t)tt * 2048;
    float gi = p[j];
    float gg = p[1024 + j];
    float go = p[1536 + j];
    float cn = sigf(gi) * tanhfast(gg);
    float hn = sigf(go) * tanhfast(cn);
    out[(size_t)node * 512 + j] = hn;
    if ((bi & 1) == 0) C256[(size_t)node * 256 + j] = cn;
}

// GEMM: gates[gl][r] = sum_k hcat[gl][k] * W_hh[r][k] + proj[type][r]
// tile: NT=16 nodes x 1024 rows (blockIdx.y half), 4 rows/thread, h-tile in LDS.
// grid (B/16, 2), block 256
__global__ __launch_bounds__(256) void gemm16_kernel(
    const int* __restrict__ a_idx, const int* __restrict__ b_idx,
    const int* __restrict__ types, const float* __restrict__ out,
    const float* __restrict__ W_hh, const float* __restrict__ proj,
    float* __restrict__ gates, int node_base) {
    __shared__ float hs[NT][512];
    int t = threadIdx.x;
    int node0 = node_base + blockIdx.x * NT;

    // gather h_cat: 16 nodes x 512 floats = 2048 float4, 8 per thread
#pragma unroll
    for (int it = 0; it < 8; ++it) {
        int idx = it * 256 + t;
        int n = idx >> 7;          // node within tile (128 float4 per node)
        int p = idx & 127;         // float4 within node
        int node = node0 + n;
        int child = (p < 64) ? a_idx[node] : b_idx[node];
        float4 v = ((const float4*)(out + (size_t)child * 512))[p & 63];
        ((float4*)&hs[n][0])[p] = v;
    }
    __syncthreads();

    int r0 = blockIdx.y * 1024 + t * 4;
    float acc[4][NT];
#pragma unroll
    for (int rr = 0; rr < 4; ++rr)
#pragma unroll
        for (int n = 0; n < NT; ++n) acc[rr][n] = 0.f;

    const float4* W4 = (const float4*)W_hh;
    for (int k4 = 0; k4 < 128; ++k4) {
        float4 h4[NT];
#pragma unroll
        for (int n = 0; n < NT; ++n) h4[n] = ((const float4*)&hs[n][0])[k4];  // LDS broadcast
#pragma unroll
        for (int rr = 0; rr < 4; ++rr) {
            float4 w = W4[(size_t)(r0 + rr) * 128 + k4];
#pragma unroll
            for (int n = 0; n < NT; ++n)
                acc[rr][n] += w.x * h4[n].x + w.y * h4[n].y + w.z * h4[n].z + w.w * h4[n].w;
        }
    }

#pragma unroll
    for (int n = 0; n < NT; ++n) {
        int node = node0 + n;
        int tt = types[node];
        float4 pv = *(const float4*)(proj + (size_t)tt * 2048 + r0);
        float4 res;
        res.x = acc[0][n] + pv.x;
        res.y = acc[1][n] + pv.y;
        res.z = acc[2][n] + pv.z;
        res.w = acc[3][n] + pv.w;
        int gl = blockIdx.x * NT + n;
        *(float4*)(gates + (size_t)gl * 2048 + r0) = res;
    }
}

// small levels (B < 16): one node per block-row, row-parallel matvec.
// grid (B, 8), block 256: rows r = blockIdx.y*256 + t
__global__ void gemm_small_kernel(
    const int* __restrict__ a_idx, const int* __restrict__ b_idx,
    const int* __restrict__ types, const float* __restrict__ out,
    const float* __restrict__ W_hh, const float* __restrict__ proj,
    float* __restrict__ gates, int node_base) {
    __shared__ float hs[512];
    int t = threadIdx.x;
    int n = blockIdx.x;
    int node = node_base + n;
    if (t < 128) {
        int child = (t < 64) ? a_idx[node] : b_idx[node];
        float4 v = ((const float4*)(out + (size_t)child * 512))[t & 63];
        ((float4*)hs)[t] = v;
    }
    __syncthreads();
    int r = blockIdx.y * 256 + t;
    const float4* w4 = (const float4*)(W_hh + (size_t)r * 512);
    const float4* h4 = (const float4*)hs;
    float acc = 0.f;
#pragma unroll 8
    for (int k = 0; k < 128; ++k) {
        float4 w = w4[k];
        float4 h = h4[k];
        acc += w.x * h.x + w.y * h.y + w.z * h.z + w.w * h.w;
    }
    int tt = types[node];
    gates[(size_t)n * 2048 + r] = acc + proj[(size_t)tt * 2048 + r];
}

// elementwise LSTM for internal nodes. grid (B*2), block 256
__global__ void lstm_kernel(const int* __restrict__ a_idx, const int* __restrict__ b_idx,
                            const float* __restrict__ gates, float* __restrict__ C256,
                            float* __restrict__ out, int node_base) {
    int bi = blockIdx.x;
    int n = bi >> 1;
    int j = ((bi & 1) << 8) + threadIdx.x;
    int node = node_base + n;
    const float* g = gates + (size_t)n * 2048;
    float gi = g[j];
    float gf = g[512 + j];
    float gg = g[1024 + j];
    float go = g[1536 + j];
    int child = (j < 256) ? a_idx[node] : b_idx[node];
    float c = C256[(size_t)child * 256 + (j & 255)];
    float cn = sigf(gf) * c + sigf(gi) * tanhfast(gg);
    float hn = sigf(go) * tanhfast(cn);
    out[(size_t)node * 512 + j] = hn;
    if ((bi & 1) == 0) C256[(size_t)node * 256 + j] = cn;
}

extern "C" void kernel_launch(void* const* d_in, const int* in_sizes, int n_in,
                              void* d_out, int out_size, void* d_ws, size_t ws_size,
                              hipStream_t stream) {
    const int* types = (const int*)d_in[0];
    const int* a_idx = (const int*)d_in[1];
    const int* b_idx = (const int*)d_in[2];
    const float* emb = (const float*)d_in[3];
    const float* W_ih = (const float*)d_in[4];
    const float* W_hh = (const float*)d_in[5];
    const float* b_ih = (const float*)d_in[6];
    const float* b_hh = (const float*)d_in[7];
    float* out = (float*)d_out;

    float* ws = (float*)d_ws;
    float* proj = ws;                          // 32*2048 = 65536 floats
    float* C256 = ws + 65536;                  // 32767*256 = 8388352 floats
    float* gates = ws + 65536 + 8388352;       // up to 8192*2048 = 16777216 floats
    // total ws use: ~96.3 MB

    proj_kernel<<<256, 256, 0, stream>>>(emb, W_ih, b_ih, b_hh, proj);
    leaf_kernel<<<32768, 256, 0, stream>>>(types, proj, out, C256);

    for (int d = 13; d >= 0; --d) {
        int base = (1 << d) - 1;
        int B = 1 << d;
        if (B >= NT) {
            gemm16_kernel<<<dim3(B / NT, 2), 256, 0, stream>>>(
                a_idx, b_idx, types, out, W_hh, proj, gates, base);
        } else {
            gemm_small_kernel<<<dim3(B, 8), 256, 0, stream>>>(
                a_idx, b_idx, types, out, W_hh, proj, gates, base);
        }
        lstm_kernel<<<B * 2, 256, 0, stream>>>(a_idx, b_idx, gates, C256, out, base);
    }
}

// Round 2
// 504.681 us; speedup vs baseline: 3.8815x; 3.8815x over previous
//
#include <hip/hip_runtime.h>
#include <hip/hip_bf16.h>

// Tree-LSTM, depth-15 complete binary tree. N=32767, state 2H=512, gates 2048.
// R2: gate GEMM moved to MFMA (bf16 split hi/lo -> ~fp32 accuracy at 3x MFMA cost).
//  - W_hh pre-swizzled into MFMA B-fragment layout (hi/lo bf16 tables, 2x2MB, coalesced loads)
//  - A (gathered child h) split into hi/lo bf16 in LDS, fragment-ready layout
//  - block tile: M=32 nodes x N=256 rows, K=512; 4 waves, each 2x4 16x16 acc tiles

#define NNODES 32767

typedef __attribute__((ext_vector_type(8))) short bf16x8;
typedef __attribute__((ext_vector_type(4))) float f32x4;

__device__ __forceinline__ float sigf(float x) { return 1.0f / (1.0f + __expf(-x)); }
__device__ __forceinline__ float tanhfast(float x) { return 2.0f / (1.0f + __expf(-2.0f * x)) - 1.0f; }

__device__ __forceinline__ short bf_hi(float x) {
    __hip_bfloat16 h = __float2bfloat16(x);
    return __builtin_bit_cast(short, h);
}
__device__ __forceinline__ float bf_f(short s) {
    __hip_bfloat16 h = __builtin_bit_cast(__hip_bfloat16, s);
    return __bfloat162float(h);
}
__device__ __forceinline__ void split8(const float* src, short* hi, short* lo) {
#pragma unroll
    for (int j = 0; j < 8; ++j) {
        float x = src[j];
        short h = bf_hi(x);
        hi[j] = h;
        lo[j] = bf_hi(x - bf_f(h));
    }
}

// proj[v][r] = dot(emb[v], W_ih[r]) + b_ih[r] + b_hh[r];  grid 256, block 256
__global__ void proj_kernel(const float* __restrict__ emb, const float* __restrict__ W_ih,
                            const float* __restrict__ b_ih, const float* __restrict__ b_hh,
                            float* __restrict__ proj) {
    __shared__ float e[256];
    int v = blockIdx.x >> 3;
    int rc = blockIdx.x & 7;
    int t = threadIdx.x;
    e[t] = emb[v * 256 + t];
    __syncthreads();
    int r = rc * 256 + t;
    const float4* w4 = (const float4*)(W_ih + (size_t)r * 256);
    const float4* e4 = (const float4*)e;
    float acc = 0.f;
#pragma unroll 8
    for (int k = 0; k < 64; ++k) {
        float4 w = w4[k];
        float4 h = e4[k];
        acc += w.x * h.x + w.y * h.y + w.z * h.z + w.w * h.w;
    }
    proj[v * 2048 + r] = acc + b_ih[r] + b_hh[r];
}

// W_hh [2048][512] fp32 -> B-fragment-layout bf16 hi/lo tables.
// frag addr: (((ntile*16 + kt)*64 + lane) * 8) shorts; lane holds n=ntile*16+(lane&15),
// k = kt*32 + (lane>>4)*8 + j.  grid 512, block 256 (131072 threads = 1 frag-lane each)
__global__ void wpack_kernel(const float* __restrict__ W_hh,
                             short* __restrict__ Whi, short* __restrict__ Wlo) {
    int t = blockIdx.x * 256 + threadIdx.x;
    int lane = t & 63;
    int kt = (t >> 6) & 15;
    int ntile = t >> 10;
    int n = ntile * 16 + (lane & 15);
    int k0 = kt * 32 + (lane >> 4) * 8;
    const float* src = W_hh + (size_t)n * 512 + k0;
    short hi[8], lo[8];
    split8(src, hi, lo);
    *(bf16x8*)(Whi + (size_t)t * 8) = *(bf16x8*)hi;
    *(bf16x8*)(Wlo + (size_t)t * 8) = *(bf16x8*)lo;
}

// leaves: gates = proj[type]; zero child state.  grid 32768, block 256
__global__ void leaf_kernel(const int* __restrict__ types, const float* __restrict__ proj,
                            float* __restrict__ out, float* __restrict__ C256) {
    int bi = blockIdx.x;
    int node = 16383 + (bi >> 1);
    int j = ((bi & 1) << 8) + threadIdx.x;
    int tt = types[node];
    const float* p = proj + (size_t)tt * 2048;
    float gi = p[j];
    float gg = p[1024 + j];
    float go = p[1536 + j];
    float cn = sigf(gi) * tanhfast(gg);
    float hn = sigf(go) * tanhfast(cn);
    out[(size_t)node * 512 + j] = hn;
    if ((bi & 1) == 0) C256[(size_t)node * 256 + j] = cn;
}

// MFMA GEMM: gates[gl][n] = sum_k hcat[gl][k]*W_hh[n][k] + proj[type][n]
// grid (B/32, 8), block 256.  LDS 64KB (A hi/lo in fragment layout).
__global__ __launch_bounds__(256) void gemm_mfma_kernel(
    const int* __restrict__ a_idx, const int* __restrict__ b_idx,
    const int* __restrict__ types, const float* __restrict__ out,
    const short* __restrict__ Whi, const short* __restrict__ Wlo,
    const float* __restrict__ proj, float* __restrict__ gates, int node_base) {
    __shared__ short Ahi[2][16][64][8];
    __shared__ short Alo[2][16][64][8];
    int t = threadIdx.x;
    int node0 = node_base + blockIdx.x * 32;

    // gather + split: 2048 fragment-lanes (2 mt x 16 kt x 64 lane), 8 per thread
#pragma unroll
    for (int it = 0; it < 8; ++it) {
        int c = it * 256 + t;
        int mt = c >> 10;
        int kt = (c >> 6) & 15;
        int lane = c & 63;
        int m_loc = mt * 16 + (lane & 15);
        int node = node0 + m_loc;
        int k0 = kt * 32 + (lane >> 4) * 8;
        int child = (k0 < 256) ? a_idx[node] : b_idx[node];
        const float* src = out + (size_t)child * 512 + (k0 & 255);
        short hi[8], lo[8];
        split8(src, hi, lo);
        *(bf16x8*)&Ahi[mt][kt][lane][0] = *(bf16x8*)hi;
        *(bf16x8*)&Alo[mt][kt][lane][0] = *(bf16x8*)lo;
    }
    __syncthreads();

    int w = t >> 6;
    int lane = t & 63;
    int ntb = blockIdx.y * 16 + w * 4;  // global ntile base for this wave

    f32x4 acc[2][4];
#pragma unroll
    for (int mt = 0; mt < 2; ++mt)
#pragma unroll
        for (int nt = 0; nt < 4; ++nt) acc[mt][nt] = (f32x4){0.f, 0.f, 0.f, 0.f};

    for (int kt = 0; kt < 16; ++kt) {
        bf16x8 ah0 = *(const bf16x8*)&Ahi[0][kt][lane][0];
        bf16x8 al0 = *(const bf16x8*)&Alo[0][kt][lane][0];
        bf16x8 ah1 = *(const bf16x8*)&Ahi[1][kt][lane][0];
        bf16x8 al1 = *(const bf16x8*)&Alo[1][kt][lane][0];
#pragma unroll
        for (int nt = 0; nt < 4; ++nt) {
            size_t off = ((size_t)((ntb + nt) * 16 + kt) * 64 + lane) * 8;
            bf16x8 bh = *(const bf16x8*)(Whi + off);
            bf16x8 bl = *(const bf16x8*)(Wlo + off);
            acc[0][nt] = __builtin_amdgcn_mfma_f32_16x16x32_bf16(ah0, bh, acc[0][nt], 0, 0, 0);
            acc[0][nt] = __builtin_amdgcn_mfma_f32_16x16x32_bf16(ah0, bl, acc[0][nt], 0, 0, 0);
            acc[0][nt] = __builtin_amdgcn_mfma_f32_16x16x32_bf16(al0, bh, acc[0][nt], 0, 0, 0);
            acc[1][nt] = __builtin_amdgcn_mfma_f32_16x16x32_bf16(ah1, bh, acc[1][nt], 0, 0, 0);
            acc[1][nt] = __builtin_amdgcn_mfma_f32_16x16x32_bf16(ah1, bl, acc[1][nt], 0, 0, 0);
            acc[1][nt] = __builtin_amdgcn_mfma_f32_16x16x32_bf16(al1, bh, acc[1][nt], 0, 0, 0);
        }
    }

    // epilogue: C/D layout col=lane&15 (n), row=(lane>>4)*4+reg (m)
#pragma unroll
    for (int mt = 0; mt < 2; ++mt) {
#pragma unroll
        for (int nt = 0; nt < 4; ++nt) {
            int n_g = (ntb + nt) * 16 + (lane & 15);
#pragma unroll
            for (int r = 0; r < 4; ++r) {
                int m_loc = mt * 16 + (lane >> 4) * 4 + r;
                int node = node0 + m_loc;
                int gl = blockIdx.x * 32 + m_loc;
                float v = acc[mt][nt][r] + proj[(size_t)types[node] * 2048 + n_g];
                gates[(size_t)gl * 2048 + n_g] = v;
            }
        }
    }
}

// small levels (B <= 16): fp32 matvec, one node per block-x, rows split over block-y
__global__ void gemm_small_kernel(
    const int* __restrict__ a_idx, const int* __restrict__ b_idx,
    const int* __restrict__ types, const float* __restrict__ out,
    const float* __restrict__ W_hh, const float* __restrict__ proj,
    float* __restrict__ gates, int node_base) {
    __shared__ float hs[512];
    int t = threadIdx.x;
    int n = blockIdx.x;
    int node = node_base + n;
    if (t < 128) {
        int child = (t < 64) ? a_idx[node] : b_idx[node];
        float4 v = ((const float4*)(out + (size_t)child * 512))[t & 63];
        ((float4*)hs)[t] = v;
    }
    __syncthreads();
    int r = blockIdx.y * 256 + t;
    const float4* w4 = (const float4*)(W_hh + (size_t)r * 512);
    const float4* h4 = (const float4*)hs;
    float acc = 0.f;
#pragma unroll 8
    for (int k = 0; k < 128; ++k) {
        float4 w = w4[k];
        float4 h = h4[k];
        acc += w.x * h.x + w.y * h.y + w.z * h.z + w.w * h.w;
    }
    int tt = types[node];
    gates[(size_t)n * 2048 + r] = acc + proj[(size_t)tt * 2048 + r];
}

// elementwise LSTM for internal nodes.  grid (B*2), block 256
__global__ void lstm_kernel(const int* __restrict__ a_idx, const int* __restrict__ b_idx,
                            const float* __restrict__ gates, float* __restrict__ C256,
                            float* __restrict__ out, int node_base) {
    int bi = blockIdx.x;
    int n = bi >> 1;
    int j = ((bi & 1) << 8) + threadIdx.x;
    int node = node_base + n;
    const float* g = gates + (size_t)n * 2048;
    float gi = g[j];
    float gf = g[512 + j];
    float gg = g[1024 + j];
    float go = g[1536 + j];
    int child = (j < 256) ? a_idx[node] : b_idx[node];
    float c = C256[(size_t)child * 256 + (j & 255)];
    float cn = sigf(gf) * c + sigf(gi) * tanhfast(gg);
    float hn = sigf(go) * tanhfast(cn);
    out[(size_t)node * 512 + j] = hn;
    if ((bi & 1) == 0) C256[(size_t)node * 256 + j] = cn;
}

extern "C" void kernel_launch(void* const* d_in, const int* in_sizes, int n_in,
                              void* d_out, int out_size, void* d_ws, size_t ws_size,
                              hipStream_t stream) {
    const int* types = (const int*)d_in[0];
    const int* a_idx = (const int*)d_in[1];
    const int* b_idx = (const int*)d_in[2];
    const float* emb = (const float*)d_in[3];
    const float* W_ih = (const float*)d_in[4];
    const float* W_hh = (const float*)d_in[5];
    const float* b_ih = (const float*)d_in[6];
    const float* b_hh = (const float*)d_in[7];
    float* out = (float*)d_out;

    float* ws = (float*)d_ws;
    float* proj = ws;                           // 32*2048 = 65536 floats (256 KB)
    float* C256 = ws + 65536;                   // 32767*256 floats (32 MB)
    float* gates = ws + 65536 + 8388352;        // 8192*2048 floats (64 MB)
    short* Whi = (short*)(ws + 65536 + 8388352 + 16777216);  // 2MB
    short* Wlo = Whi + 2048 * 512;                           // 2MB
    // total ws use ~100.3 MB

    proj_kernel<<<256, 256, 0, stream>>>(emb, W_ih, b_ih, b_hh, proj);
    wpack_kernel<<<512, 256, 0, stream>>>(W_hh, Whi, Wlo);
    leaf_kernel<<<32768, 256, 0, stream>>>(types, proj, out, C256);

    for (int d = 13; d >= 0; --d) {
        int base = (1 << d) - 1;
        int B = 1 << d;
        if (B >= 32) {
            gemm_mfma_kernel<<<dim3(B / 32, 8), 256, 0, stream>>>(
                a_idx, b_idx, types, out, Whi, Wlo, proj, gates, base);
        } else {
            gemm_small_kernel<<<dim3(B, 8), 256, 0, stream>>>(
                a_idx, b_idx, types, out, W_hh, proj, gates, base);
        }
        lstm_kernel<<<B * 2, 256, 0, stream>>>(a_idx, b_idx, gates, C256, out, base);
    }
}